// Round 1
// 1046.071 us; speedup vs baseline: 1.0039x; 1.0039x over previous
//
#include <hip/hip_runtime.h>
#include <hip/hip_bf16.h>

// OnlineLayer: res-LN + conv + per-partition graph aggregation (the big GEMM vs
// A: 3x8192x8192 fp32 = 805MB, streamed once -> HBM-bound ~128us floor) + FIFO
// step + LN/ReLU epilogue.
//
// R1 changes vs baseline:
//  * k2: 3-buffer stage-1-ahead pipeline with counted s_waitcnt vmcnt(6) + raw
//    s_barrier (never drains to 0 in steady state). h-frags are prefetched one
//    chunk ahead and issued BEFORE the stage loads, so the compiler's frag wait
//    no longer forces vmcnt(0) (baseline bug: frag loads were the youngest vmem
//    ops -> every chunk fully drained the "async" prefetch).
//  * split-K atomics -> plain-stored partials (y_part[16]); reduced in k3.
//  * stats atomics/memsets -> per-block partial sums; reduced in k4.
//  * graph is now 4 dispatches, no memsets.
//
// ws layout (bytes):
//   [0, 1572864)           h bf16       (96 x 8192)
//   [1572864, 18350080)    y_part f32   (16 x 32 x 8192) split-K partials
//   [18350080, 19398656)   agg f32      (32 x 8192)
//   [19398656, 20447232)   res f32      (32 x 8192)
//   [20447232, 20447488)   res_part f32 (32 x {sum, sumsq})
//   [20447488, 20449536)   agg_part f32 (256 x {sum, sumsq})

#define PP 3
#define CIN 64
#define COUT 32
#define VV 8192
#define EPSL 1e-5f
#define SPLITK 16

typedef short v8s __attribute__((ext_vector_type(8)));
typedef float v4f __attribute__((ext_vector_type(4)));

// ---------------- block reduce (2 values) + single store ----------------
__device__ __forceinline__ void block_reduce2_store(float s1, float s2,
                                                    float* dst) {
  #pragma unroll
  for (int off = 32; off > 0; off >>= 1) {
    s1 += __shfl_down(s1, off, 64);
    s2 += __shfl_down(s2, off, 64);
  }
  __shared__ float r1[4], r2[4];
  int lane = threadIdx.x & 63, wv = threadIdx.x >> 6;
  if (lane == 0) { r1[wv] = s1; r2[wv] = s2; }
  __syncthreads();
  if (threadIdx.x == 0) {
    dst[0] = r1[0] + r1[1] + r1[2] + r1[3];
    dst[1] = r2[0] + r2[1] + r2[2] + r2[3];
  }
}

// ---------------- K1: convs (h bf16, res f32) + res stat partials ----------------
// grid (32, 4), block 256. og 0..2 -> h rows og*32..og*32+31 ; og 3 -> res.
__global__ __launch_bounds__(256) void k1_conv(
    const float* __restrict__ x, const float* __restrict__ conv_w,
    const float* __restrict__ conv_b, const float* __restrict__ res_w,
    __hip_bfloat16* __restrict__ h, float* __restrict__ res,
    float* __restrict__ res_part) {
  int v = blockIdx.x * 256 + threadIdx.x;
  int og = blockIdx.y;
  float xr[CIN];
  #pragma unroll
  for (int c = 0; c < CIN; ++c) xr[c] = x[c * VV + v];

  if (og < 3) {
    for (int i = 0; i < 32; ++i) {
      int o = og * 32 + i;
      float acc = conv_b[o];
      #pragma unroll
      for (int c = 0; c < CIN; ++c) acc = fmaf(conv_w[o * CIN + c], xr[c], acc);
      h[o * VV + v] = __float2bfloat16(acc);
    }
  } else {
    float s1 = 0.f, s2 = 0.f;
    for (int o = 0; o < COUT; ++o) {
      float acc = 0.f;
      #pragma unroll
      for (int c = 0; c < CIN; ++c) acc = fmaf(res_w[o * CIN + c], xr[c], acc);
      res[o * VV + v] = acc;
      s1 += acc; s2 += acc * acc;
    }
    block_reduce2_store(s1, s2, &res_part[blockIdx.x * 2]);
  }
}

// ---------------- K2: y_part[kb] = h @ A slice (the HBM-bound GEMM) ----------------
// M=32 (c), N tile 128 (w), split-K 16, K-chunk 32.
// LDS chunk layout: 16 row-pairs; pair pr = rows (2pr, 2pr+1), 1024B data +
// 16B pad (stride 1040B = 260 dwords) -> 2-way-bank (free) frag reads, and
// global_load_lds's lane-contiguous dest constraint is satisfied per pair.
//
// Pipeline: 3 buffers, stage chunk c+1 while computing c. Per-wave vmem order
// per iter: [h(c+1): 2 loads][stage(c+1): 4 global_load_lds] -> vmcnt(6)
// retires everything older (h(c), stage(c)) and keeps exactly the next chunk
// in flight across the barrier. Writer (c+1)%3 vs slowest reader (c-1)%3
// differ by 2 mod 3 -> no buffer race without an end-of-chunk barrier.
#define TN 128
#define KC 32
#define CHUNKS 48
#define PAIR_DW 260
#define PAIR_BYTES 1040
#define BUF_BYTES (16 * PAIR_BYTES)

__global__ __launch_bounds__(256) void k2_gemm(
    const float* __restrict__ A, const __hip_bfloat16* __restrict__ h,
    float* __restrict__ y_part) {
  __shared__ char lds_raw[3][BUF_BYTES];
  const int tid = threadIdx.x;
  const int wv = tid >> 6, lane = tid & 63;
  const int quad = lane >> 4, l15 = lane & 15;
  const int wbase = blockIdx.x * TN;
  const int kbase = blockIdx.y * (KC * CHUNKS);
  const int srow = lane >> 5;          // row within pair
  const int scol = (lane & 31) * 4;    // float col within tile

  v4f acc[2][2] = {};

  auto stage = [&](char* buf, int chunk) {
    int k0 = kbase + chunk * KC;
    int p = k0 >> 13, v0 = k0 & (VV - 1);
    const float* Ap = A + ((size_t)p << 26);
    for (int pr = wv; pr < 16; pr += 4) {   // exactly 4 loads per wave
      const float* gp = Ap + (size_t)(v0 + 2 * pr + srow) * VV + wbase + scol;
      void* lp = (void*)(buf + pr * PAIR_BYTES);
      __builtin_amdgcn_global_load_lds(
          (const __attribute__((address_space(1))) void*)gp,
          (__attribute__((address_space(3))) void*)lp, 16, 0, 0);
    }
  };

  // prologue: h frags for chunk 0 (2 loads), then stage chunk 0 (4 loads)
  {
    int p0 = kbase >> 13, v00 = kbase & (VV - 1);
    // (prologue loads issued below, same order as steady state)
    const __hip_bfloat16* hp0 = h + (size_t)(p0 * COUT + l15) * VV + v00 + quad * 8;
    // nothing older in flight; vmcnt(6) at c=0 retires these 6.
    // frag regs:
    // (declared after to keep SSA simple)
    v8s tmp0 = *(const v8s*)hp0;
    v8s tmp1 = *(const v8s*)(hp0 + 16 * VV);
    stage(lds_raw[0], 0);

    v8s hfr0 = tmp0, hfr1 = tmp1;

    for (int c = 0; c < CHUNKS; ++c) {
      v8s hn0 = hfr0, hn1 = hfr1;  // benign init; overwritten unless last iter
      if (c + 1 < CHUNKS) {
        int kk = kbase + (c + 1) * KC;
        int p = kk >> 13, v0n = kk & (VV - 1);
        const __hip_bfloat16* hpn =
            h + (size_t)(p * COUT + l15) * VV + v0n + quad * 8;
        hn0 = *(const v8s*)hpn;                 // 1 global_load_dwordx4
        hn1 = *(const v8s*)(hpn + 16 * VV);     // 1 global_load_dwordx4
        stage(lds_raw[(c + 1) % 3], c + 1);     // 4 global_load_lds
        asm volatile("s_waitcnt vmcnt(6)" ::: "memory");  // keep only c+1 in flight
      } else {
        asm volatile("s_waitcnt vmcnt(0)" ::: "memory");  // final drain
      }
      __builtin_amdgcn_s_barrier();
      asm volatile("" ::: "memory");  // fence: no ds_read hoists above barrier

      const float* lf = (const float*)lds_raw[c % 3];

      #pragma unroll
      for (int nt = 0; nt < 2; ++nt) {
        int wl = wv * 32 + nt * 16 + l15;
        union { unsigned u[4]; v8s s; } bf;
        #pragma unroll
        for (int t = 0; t < 4; ++t) {
          int pr = quad * 4 + t;  // k elems 2t,2t+1 -> rows (quad*8+2t, +1)
          float f0 = lf[pr * PAIR_DW + wl];
          float f1 = lf[pr * PAIR_DW + 128 + wl];
          // pack hi16(f1):hi16(f0)  (bf16 truncation)
          bf.u[t] = __builtin_amdgcn_perm(__float_as_uint(f1),
                                          __float_as_uint(f0), 0x07060302u);
        }
        acc[0][nt] = __builtin_amdgcn_mfma_f32_16x16x32_bf16(hfr0, bf.s, acc[0][nt], 0, 0, 0);
        acc[1][nt] = __builtin_amdgcn_mfma_f32_16x16x32_bf16(hfr1, bf.s, acc[1][nt], 0, 0, 0);
      }
      hfr0 = hn0; hfr1 = hn1;
      // no end-of-chunk barrier: 3-buffer distance guards reuse
    }
  }

  // C/D: col(w)=lane&15, row(c)=(lane>>4)*4+reg  [m89/m91]
  float* yp = y_part + (size_t)blockIdx.y * COUT * VV;
  #pragma unroll
  for (int mt = 0; mt < 2; ++mt)
    #pragma unroll
    for (int nt = 0; nt < 2; ++nt)
      #pragma unroll
      for (int r = 0; r < 4; ++r) {
        int crow = mt * 16 + quad * 4 + r;
        int w = wbase + wv * 32 + nt * 16 + l15;
        yp[(size_t)crow * VV + w] = acc[mt][nt][r];
      }
}

// ---------------- K3: agg = acc + sum_k y_part[k] - fifo + stat partials ----------------
__global__ __launch_bounds__(256) void k3_agg(
    const float* __restrict__ acc_slot, const float* __restrict__ fifo,
    const float* __restrict__ y_part, float* __restrict__ agg,
    float* __restrict__ agg_part) {
  int i = blockIdx.x * 256 + threadIdx.x;  // float4 index (65536 total)
  float4 s = ((const float4*)y_part)[i];
  #pragma unroll
  for (int kb = 1; kb < SPLITK; ++kb) {
    float4 t = ((const float4*)(y_part + (size_t)kb * COUT * VV))[i];
    s.x += t.x; s.y += t.y; s.z += t.z; s.w += t.w;
  }
  float4 av = ((const float4*)acc_slot)[i];
  float4 fv = ((const float4*)fifo)[i];
  float4 g;
  g.x = av.x + s.x - fv.x;
  g.y = av.y + s.y - fv.y;
  g.z = av.z + s.z - fv.z;
  g.w = av.w + s.w - fv.w;
  ((float4*)agg)[i] = g;
  float s1 = g.x + g.y + g.z + g.w;
  float s2 = g.x * g.x + g.y * g.y + g.z * g.z + g.w * g.w;
  block_reduce2_store(s1, s2, &agg_part[blockIdx.x * 2]);
}

// ---------------- K4: reduce partials; out = relu(relu(LN(agg)) + LN(res)) ----------------
__global__ __launch_bounds__(256) void k4_final(
    const float* __restrict__ agg, const float* __restrict__ res,
    const float* __restrict__ ln_w, const float* __restrict__ ln_b,
    const float* __restrict__ res_ln_w, const float* __restrict__ res_ln_b,
    const float* __restrict__ res_part, const float* __restrict__ agg_part,
    float* __restrict__ out) {
  __shared__ float sf[4];
  if (threadIdx.x < 64) {
    int lane = threadIdx.x;
    float a1 = 0.f, a2 = 0.f;
    #pragma unroll
    for (int j = 0; j < 4; ++j) {
      a1 += agg_part[2 * (lane + 64 * j)];
      a2 += agg_part[2 * (lane + 64 * j) + 1];
    }
    float r1 = 0.f, r2 = 0.f;
    if (lane < 32) { r1 = res_part[2 * lane]; r2 = res_part[2 * lane + 1]; }
    #pragma unroll
    for (int off = 32; off > 0; off >>= 1) {
      a1 += __shfl_down(a1, off, 64);
      a2 += __shfl_down(a2, off, 64);
      r1 += __shfl_down(r1, off, 64);
      r2 += __shfl_down(r2, off, 64);
    }
    if (lane == 0) {
      const float inv_n = 1.0f / (COUT * VV);
      float mr = r1 * inv_n;
      float vr = r2 * inv_n - mr * mr;
      float ma = a1 * inv_n;
      float va = a2 * inv_n - ma * ma;
      sf[0] = mr; sf[1] = rsqrtf(vr + EPSL);
      sf[2] = ma; sf[3] = rsqrtf(va + EPSL);
    }
  }
  __syncthreads();
  const float mr = sf[0], rsr = sf[1], ma = sf[2], rsa = sf[3];

  int i = blockIdx.x * 256 + threadIdx.x;
  float4 g = ((const float4*)agg)[i];
  float4 r = ((const float4*)res)[i];
  float4 w1 = ((const float4*)ln_w)[i], b1 = ((const float4*)ln_b)[i];
  float4 w2 = ((const float4*)res_ln_w)[i], b2 = ((const float4*)res_ln_b)[i];
  float4 o;
  o.x = fmaxf(fmaxf((g.x - ma) * rsa * w1.x + b1.x, 0.f) + (r.x - mr) * rsr * w2.x + b2.x, 0.f);
  o.y = fmaxf(fmaxf((g.y - ma) * rsa * w1.y + b1.y, 0.f) + (r.y - mr) * rsr * w2.y + b2.y, 0.f);
  o.z = fmaxf(fmaxf((g.z - ma) * rsa * w1.z + b1.z, 0.f) + (r.z - mr) * rsr * w2.z + b2.z, 0.f);
  o.w = fmaxf(fmaxf((g.w - ma) * rsa * w1.w + b1.w, 0.f) + (r.w - mr) * rsr * w2.w + b2.w, 0.f);
  ((float4*)out)[i] = o;
}

extern "C" void kernel_launch(void* const* d_in, const int* in_sizes, int n_in,
                              void* d_out, int out_size, void* d_ws, size_t ws_size,
                              hipStream_t stream) {
  const float* x        = (const float*)d_in[0];
  const float* A        = (const float*)d_in[1];
  const float* conv_w   = (const float*)d_in[2];
  const float* conv_b   = (const float*)d_in[3];
  const float* fifo     = (const float*)d_in[4];
  const float* acc_slot = (const float*)d_in[5];
  const float* ln_w     = (const float*)d_in[6];
  const float* ln_b     = (const float*)d_in[7];
  const float* res_w    = (const float*)d_in[8];
  const float* res_ln_w = (const float*)d_in[9];
  const float* res_ln_b = (const float*)d_in[10];
  float* out = (float*)d_out;

  char* ws = (char*)d_ws;
  __hip_bfloat16* h  = (__hip_bfloat16*)ws;
  float* y_part   = (float*)(ws + 1572864);
  float* agg      = (float*)(ws + 18350080);
  float* res      = (float*)(ws + 19398656);
  float* res_part = (float*)(ws + 20447232);
  float* agg_part = (float*)(ws + 20447488);

  k1_conv<<<dim3(32, 4), 256, 0, stream>>>(x, conv_w, conv_b, res_w, h, res, res_part);
  k2_gemm<<<dim3(VV / TN, SPLITK), 256, 0, stream>>>(A, h, y_part);
  k3_agg<<<256, 256, 0, stream>>>(acc_slot, fifo, y_part, agg, agg_part);
  k4_final<<<256, 256, 0, stream>>>(agg, res, ln_w, ln_b, res_ln_w, res_ln_b,
                                    res_part, agg_part, out);
}